// Round 5
// baseline (676.447 us; speedup 1.0000x reference)
//
#include <hip/hip_runtime.h>

#define S_LEN 2048
#define HID 2048
#define NH 16
#define NKV 2
#define HD 256
#define MAXSEQ 4096
#define NALL 9216   // 8192 qg | 512 k | 512 v
#define RD 64

typedef __attribute__((ext_vector_type(8))) short short8_t;   // 8 bf16 (4 VGPRs)
typedef __attribute__((ext_vector_type(4))) float float4_t;   // MFMA C/D

// DPP cross-lane over a 16-lane row (VALU pipe, not LDS): xor1, xor2, half-mirror, mirror
#define DPPF(x, ctrl) __builtin_bit_cast(float, __builtin_amdgcn_update_dpp( \
    __builtin_bit_cast(int, x), __builtin_bit_cast(int, x), ctrl, 0xF, 0xF, false))

__device__ __forceinline__ unsigned short f2b(float f) {
  union { float f; unsigned u; } v; v.f = f;
  unsigned u = v.u;
  return (unsigned short)((u + 0x7FFFu + ((u >> 16) & 1u)) >> 16);  // RNE, finite data
}

__device__ __forceinline__ void gload_lds16(const void* g, void* l) {
  __builtin_amdgcn_global_load_lds(
      (const __attribute__((address_space(1))) void*)g,
      (__attribute__((address_space(3))) void*)l, 16, 0, 0);
}

// ---------------- fused fp32->bf16 converts + cache-pad zeroing (one dispatch) ----------------
__global__ void fused_cvt(const float* __restrict__ hidden, const float* __restrict__ qw,
                          const float* __restrict__ kw, const float* __restrict__ vw,
                          const float* __restrict__ ow,
                          unsigned short* __restrict__ hidb, unsigned short* __restrict__ wallb,
                          unsigned short* __restrict__ wob,
                          float* __restrict__ kcache, float* __restrict__ vcache) {
  const long i = (long)blockIdx.x * 256 + threadIdx.x;
  const long N0 = 1048576, N1 = N0 + 4194304, N2 = N1 + 262144, N3 = N2 + 262144,
             N4 = N3 + 2097152;
  if (i < N4) {
    const float* s; unsigned short* d; long j;
    if (i < N0)      { s = hidden; d = hidb;  j = i; }
    else if (i < N1) { s = qw; d = wallb;                        j = i - N0; }
    else if (i < N2) { s = kw; d = wallb + (size_t)8192*HID;     j = i - N1; }
    else if (i < N3) { s = vw; d = wallb + (size_t)8704*HID;     j = i - N2; }
    else             { s = ow; d = wob;                          j = i - N3; }
    float4 v = ((const float4*)s)[j];
    short4 o;
    o.x = (short)f2b(v.x); o.y = (short)f2b(v.y);
    o.z = (short)f2b(v.z); o.w = (short)f2b(v.w);
    ((short4*)d)[j] = o;
  } else {
    long j = i - N4;                 // 0 .. 524287
    int region = (int)(j >> 17);     // 131072 float4 per pad region
    long o = j & 131071;
    float* base = (region < 2 ? kcache : vcache)
                + (size_t)(region & 1) * MAXSEQ * HD + (size_t)S_LEN * HD;
    float4 z; z.x = 0.f; z.y = 0.f; z.z = 0.f; z.w = 0.f;
    ((float4*)base)[o] = z;
  }
}

// ---------------- bf16 GEMM, C = A * B^T  (A: MxK, B: NxK row-major, C: MxN f32) ----------------
// m97 structure + BK=64 + XOR-swizzled LDS (chunk' = chunk ^ (row&7)).
template<int BM, int BN, int MI, int NI>
__global__ __launch_bounds__(256, 2) void gemm_bt(
    const unsigned short* __restrict__ A, const unsigned short* __restrict__ B,
    float* __restrict__ C, int M, int N, int K) {
  constexpr int BK = 64;
  __shared__ unsigned short As[BM * BK];
  __shared__ unsigned short Bs[BN * BK];
  const int tid = threadIdx.x;
  const int lane = tid & 63;
  const int w = tid >> 6;
  const int wr = w >> 1, wc = w & 1;
  const int l15 = lane & 15, l4 = lane >> 4;
  const int M0 = blockIdx.y * BM, N0 = blockIdx.x * BN;
  float4_t acc[MI][NI] = {};
  for (int kt = 0; kt < K; kt += BK) {
    __syncthreads();
#pragma unroll
    for (int i = 0; i < BM/32; ++i) {
      int c = tid + i*256;
      int row = c >> 3;
      gload_lds16(A + (size_t)(M0 + row)*K + kt + ((c & 7) ^ (row & 7))*8, (char*)As + c*16);
    }
#pragma unroll
    for (int i = 0; i < BN/32; ++i) {
      int c = tid + i*256;
      int row = c >> 3;
      gload_lds16(B + (size_t)(N0 + row)*K + kt + ((c & 7) ^ (row & 7))*8, (char*)Bs + c*16);
    }
    __syncthreads();
#pragma unroll
    for (int ks = 0; ks < 2; ++ks) {
      short8_t af[MI], bf[NI];
#pragma unroll
      for (int mi = 0; mi < MI; ++mi) {
        int row = wr*(BM/2) + mi*16 + l15;
        af[mi] = *(const short8_t*)&As[row*BK + ((ks*4 + l4) ^ (l15 & 7))*8];
      }
#pragma unroll
      for (int ni = 0; ni < NI; ++ni) {
        int row = wc*(BN/2) + ni*16 + l15;
        bf[ni] = *(const short8_t*)&Bs[row*BK + ((ks*4 + l4) ^ (l15 & 7))*8];
      }
#pragma unroll
      for (int mi = 0; mi < MI; ++mi)
#pragma unroll
        for (int ni = 0; ni < NI; ++ni)
          acc[mi][ni] = __builtin_amdgcn_mfma_f32_16x16x32_bf16(af[mi], bf[ni], acc[mi][ni], 0, 0, 0);
    }
  }
#pragma unroll
  for (int mi = 0; mi < MI; ++mi) {
    int rb = M0 + wr*(BM/2) + mi*16 + l4*4;
#pragma unroll
    for (int ni = 0; ni < NI; ++ni) {
      int col = N0 + wc*(BN/2) + ni*16 + l15;
#pragma unroll
      for (int r = 0; r < 4; ++r)
        C[(size_t)(rb + r)*N + col] = acc[mi][ni][r];
    }
  }
}

// ---------------- post: RMSNorm + RoPE + split + caches + V^T ----------------
__global__ void postproc(const float* __restrict__ C1,
                         const float* __restrict__ cosb, const float* __restrict__ sinb,
                         const float* __restrict__ qnw, const float* __restrict__ knw,
                         unsigned short* __restrict__ qb, unsigned short* __restrict__ kb,
                         unsigned short* __restrict__ vtb,
                         float* __restrict__ kcache, float* __restrict__ vcache) {
  const int w = threadIdx.x >> 6, lane = threadIdx.x & 63;
  const int s = blockIdx.x*4 + w;
  const int t = blockIdx.y;
  const int d = lane*4;
  const float* rowp;
  if (t < 16)      rowp = C1 + (size_t)s*NALL + t*512;
  else if (t < 18) rowp = C1 + (size_t)s*NALL + 8192 + (t-16)*256;
  else             rowp = C1 + (size_t)s*NALL + 8704 + (t-18)*256;
  float4 x = *(const float4*)(rowp + d);
  if (t >= 18) {
    int kvi = t - 18;
    *(float4*)(vcache + (size_t)kvi*MAXSEQ*HD + (size_t)s*HD + d) = x;
    unsigned short* vt = vtb + (size_t)kvi*HD*S_LEN;
    vt[(size_t)(d+0)*S_LEN + s] = f2b(x.x);
    vt[(size_t)(d+1)*S_LEN + s] = f2b(x.y);
    vt[(size_t)(d+2)*S_LEN + s] = f2b(x.z);
    vt[(size_t)(d+3)*S_LEN + s] = f2b(x.w);
    return;
  }
  float ss = x.x*x.x + x.y*x.y + x.z*x.z + x.w*x.w;
#pragma unroll
  for (int o = 32; o >= 1; o >>= 1) ss += __shfl_xor(ss, o, 64);
  float rn = rsqrtf(ss*(1.0f/256.0f) + 1e-6f);
  const float* nw = (t < 16) ? qnw : knw;
  float4 g = *(const float4*)(nw + d);
  float4 y;
  y.x = x.x*rn*(1.f+g.x); y.y = x.y*rn*(1.f+g.y);
  y.z = x.z*rn*(1.f+g.z); y.w = x.w*rn*(1.f+g.w);
  float px = __shfl_xor(y.x, 8, 64);
  float py = __shfl_xor(y.y, 8, 64);
  float pz = __shfl_xor(y.z, 8, 64);
  float pw = __shfl_xor(y.w, 8, 64);
  if (lane < 16) {
    float sgn = (lane & 8) ? 1.f : -1.f;
    float4 cs = *(const float4*)(cosb + (size_t)s*RD + d);
    float4 sn = *(const float4*)(sinb + (size_t)s*RD + d);
    y.x = y.x*cs.x + sgn*px*sn.x;
    y.y = y.y*cs.y + sgn*py*sn.y;
    y.z = y.z*cs.z + sgn*pz*sn.z;
    y.w = y.w*cs.w + sgn*pw*sn.w;
  }
  if (t < 16) {
    const float qs = 0.0625f * 1.44269504088896f;
    short4 o;
    o.x = (short)f2b(y.x*qs); o.y = (short)f2b(y.y*qs);
    o.z = (short)f2b(y.z*qs); o.w = (short)f2b(y.w*qs);
    *(short4*)(qb + (size_t)t*S_LEN*HD + (size_t)s*HD + d) = o;
  } else {
    int kvi = t - 16;
    *(float4*)(kcache + (size_t)kvi*MAXSEQ*HD + (size_t)s*HD + d) = y;
    short4 o;
    o.x = (short)f2b(y.x); o.y = (short)f2b(y.y);
    o.z = (short)f2b(y.z); o.w = (short)f2b(y.w);
    *(short4*)(kb + (size_t)kvi*S_LEN*HD + (size_t)s*HD + d) = o;
  }
}

// ---------------- flash attention + fused sigmoid gate ----------------
// R9: 32 q-rows per wave (2 A-frags) — halves LDS reads per unit work.
// Block = 256 thr / 4 waves: w&1 = row-half (rows wv*32..wv*32+31 of the
// 64-row q-tile), w>>1 = split-K group (A: tiles [0,qt+1), B: [qt+1,2qt+2)).
// Same 32 K/V LDS reads per wave-iter now feed 64 MFMA (was 32) ->
// LDS-pipe floor ~26us. Complement remap + verified sync skeleton from R8:
//   B1 __syncthreads; stage K(8)+V(8) by 128-thr group; vmcnt(8) [K landed,
//   V in flight]; s_barrier (B2); QK+softmax+P; __syncthreads (B3 = V drain); PV.
// __launch_bounds__(256,2): 2 waves/SIMD -> 256-VGPR cap (est. use ~245).
// LDS 72KB: 2x Ks 32x256 | 2x VTs 256x32 | 4x Pw 32x32 -> 2 blk/CU (144KB).
// Defer-max THR=4 kept (exact). Merge: B dumps (m,l,O), A combines+gate+store.
__global__ __launch_bounds__(256, 2) void attn_kernel(
    const unsigned short* __restrict__ qb, const unsigned short* __restrict__ kb,
    const unsigned short* __restrict__ vtb, const float* __restrict__ C1,
    unsigned short* __restrict__ attnb) {
  __shared__ char smem[73728];
  const int tid = threadIdx.x, lane = tid & 63, w = tid >> 6;  // w: 0..3
  const int g  = w >> 1;          // k-split group (0 = low half, 1 = high half)
  const int wv = w & 1;           // row-half: q rows [wv*32, wv*32+32)
  const int gtid = tid & 127;     // thread id within group (staging, 128 thr)
  const int l15 = lane & 15, l4 = lane >> 4;
  unsigned short* Ks  = (unsigned short*)(smem + g*16384);          // 32 x 256
  unsigned short* VTs = (unsigned short*)(smem + 32768 + g*16384);  // 256 x 32
  unsigned short* Pw  = (unsigned short*)(smem + 65536 + w*2048);   // private 32x32
  const int b = blockIdx.x;
  const int i2 = b & 255;
  const int h = i2 & 15;
  const int t16 = i2 >> 4;                     // 0..15
  const int qt = (b < 256) ? t16 : (31 - t16); // complement remap
  const int kv = h >> 3;                       // GROUPS = 8
  const int q0 = qt * 64;
  const unsigned short* Qb = qb + (size_t)h*S_LEN*HD;
  const unsigned short* Kb = kb + (size_t)kv*S_LEN*HD;
  const unsigned short* Vb = vtb + (size_t)kv*HD*S_LEN;
  short8_t qf[2][8];                           // 2 A-frags (rows fr*16 block)
#pragma unroll
  for (int fr = 0; fr < 2; ++fr) {
    const int qrow = q0 + wv*32 + fr*16 + l15;
#pragma unroll
    for (int kk = 0; kk < 8; ++kk)
      qf[fr][kk] = *(const short8_t*)(Qb + (size_t)qrow*HD + kk*32 + l4*8);
  }
  float4_t oacc[2][16] = {};
  float m_run[2][4] = {{-1e30f,-1e30f,-1e30f,-1e30f},{-1e30f,-1e30f,-1e30f,-1e30f}};
  float l_run[2][4] = {};
  const int nIt = qt + 1;                     // iterations per group (equal!)
  const int tbase = g * nIt;                  // first global 32-tile index
  for (int it = 0; it < nIt; ++it) {
    const int tIdx = tbase + it;
    const int k0 = tIdx * 32;
    __syncthreads();                          // B1: prev iter's LDS reads done
#pragma unroll
    for (int i = 0; i < 8; ++i) {             // K tile: 32 rows x 256, swizzled src col
      int c = gtid + i*128;
      int row = c >> 5;
      gload_lds16(Kb + (size_t)(k0 + row)*HD + ((c & 31) ^ (row & 7))*8, (char*)Ks + c*16);
    }
#pragma unroll
    for (int i = 0; i < 8; ++i) {             // V^T tile: 256 rows x 32
      int c = gtid + i*128;
      int row = c >> 2;
      gload_lds16(Vb + (size_t)row*S_LEN + k0 + ((c & 3) ^ ((row >> 1) & 3))*8, (char*)VTs + c*16);
    }
    asm volatile("s_waitcnt vmcnt(8)" ::: "memory");  // own K landed; V still in flight
    __builtin_amdgcn_s_barrier();             // B2: all waves' K in LDS
    __builtin_amdgcn_sched_barrier(0);
    float4_t sacc[2][2] = {};
#pragma unroll
    for (int kk = 0; kk < 8; ++kk) {          // 2 K-frag reads feed 4 MFMA
      short8_t b0 = *(const short8_t*)&Ks[(l15)*HD      + ((kk*4 + l4) ^ (l15 & 7))*8];
      short8_t b1 = *(const short8_t*)&Ks[(16 + l15)*HD + ((kk*4 + l4) ^ (l15 & 7))*8];
      sacc[0][0] = __builtin_amdgcn_mfma_f32_16x16x32_bf16(qf[0][kk], b0, sacc[0][0], 0, 0, 0);
      sacc[0][1] = __builtin_amdgcn_mfma_f32_16x16x32_bf16(qf[0][kk], b1, sacc[0][1], 0, 0, 0);
      sacc[1][0] = __builtin_amdgcn_mfma_f32_16x16x32_bf16(qf[1][kk], b0, sacc[1][0], 0, 0, 0);
      sacc[1][1] = __builtin_amdgcn_mfma_f32_16x16x32_bf16(qf[1][kk], b1, sacc[1][1], 0, 0, 0);
    }
    if (tIdx >= 2*qt) {                       // causal mask only on diagonal tiles
#pragma unroll
      for (int fr = 0; fr < 2; ++fr)
#pragma unroll
        for (int nt = 0; nt < 2; ++nt)
#pragma unroll
          for (int r = 0; r < 4; ++r)
            if (k0 + nt*16 + l15 > q0 + wv*32 + fr*16 + l4*4 + r) sacc[fr][nt][r] = -1e30f;
    }
    float m0[2][4], p[2][2][4];
#pragma unroll
    for (int fr = 0; fr < 2; ++fr)
#pragma unroll
      for (int r = 0; r < 4; ++r) {
        float v = fmaxf(sacc[fr][0][r], sacc[fr][1][r]);
        v = fmaxf(v, DPPF(v, 0xB1));          // quad_perm xor1
        v = fmaxf(v, DPPF(v, 0x4E));          // quad_perm xor2
        v = fmaxf(v, DPPF(v, 0x141));         // row_half_mirror
        v = fmaxf(v, DPPF(v, 0x140));         // row_mirror -> 16-lane max
        m0[fr][r] = v;
      }
    int need = 0;
#pragma unroll
    for (int fr = 0; fr < 2; ++fr)
#pragma unroll
      for (int r = 0; r < 4; ++r)
        need |= (m0[fr][r] > m_run[fr][r] + 4.f);
    if (__any(need)) {                        // wave-uniform: rescale path
#pragma unroll
      for (int fr = 0; fr < 2; ++fr) {
        float al[4];
#pragma unroll
        for (int r = 0; r < 4; ++r) {
          float mnew = fmaxf(m_run[fr][r], m0[fr][r]);
          al[r] = exp2f(m_run[fr][r] - mnew);
          m_run[fr][r] = mnew;
          l_run[fr][r] *= al[r];
        }
#pragma unroll
        for (int nt2 = 0; nt2 < 16; ++nt2) {
          oacc[fr][nt2][0] *= al[0];
          oacc[fr][nt2][1] *= al[1];
          oacc[fr][nt2][2] *= al[2];
          oacc[fr][nt2][3] *= al[3];
        }
      }
    }
#pragma unroll
    for (int fr = 0; fr < 2; ++fr)
#pragma unroll
      for (int r = 0; r < 4; ++r) {
        p[fr][0][r] = exp2f(sacc[fr][0][r] - m_run[fr][r]);  // bounded by 2^4
        p[fr][1][r] = exp2f(sacc[fr][1][r] - m_run[fr][r]);
        float sum = p[fr][0][r] + p[fr][1][r];
        sum += DPPF(sum, 0xB1);
        sum += DPPF(sum, 0x4E);
        sum += DPPF(sum, 0x141);
        sum += DPPF(sum, 0x140);              // 16-lane sum
        l_run[fr][r] += sum;
      }
    // P: D-layout -> A-layout via private LDS (same-wave RAW, lgkmcnt suffices)
#pragma unroll
    for (int fr = 0; fr < 2; ++fr)
#pragma unroll
      for (int nt = 0; nt < 2; ++nt)
#pragma unroll
        for (int r = 0; r < 4; ++r) {
          int prow = fr*16 + l4*4 + r;
          int pcol = nt*16 + l15;
          Pw[prow*32 + (((pcol >> 3) ^ ((prow >> 1) & 3)))*8 + (pcol & 7)] = f2b(p[fr][nt][r]);
        }
    short8_t pf0 = *(const short8_t*)&Pw[(l15)*32      + ((l4 ^ ((l15 >> 1) & 3)))*8];
    short8_t pf1 = *(const short8_t*)&Pw[(16 + l15)*32 + ((l4 ^ (((16 + l15) >> 1) & 3)))*8];
    __syncthreads();                          // B3: drains vmcnt(0) = V landed, all waves
#pragma unroll
    for (int nt2 = 0; nt2 < 16; ++nt2) {      // 1 V-frag read feeds 2 MFMA
      int vrow = nt2*16 + l15;
      short8_t v0 = *(const short8_t*)&VTs[vrow*32 + ((l4 ^ ((vrow >> 1) & 3)))*8];
      oacc[0][nt2] = __builtin_amdgcn_mfma_f32_16x16x32_bf16(pf0, v0, oacc[0][nt2], 0, 0, 0);
      oacc[1][nt2] = __builtin_amdgcn_mfma_f32_16x16x32_bf16(pf1, v0, oacc[1][nt2], 0, 0, 0);
    }
  }
  // ------- in-block split-K merge: B dumps to LDS, A combines + gate + store -------
  __syncthreads();                            // all LDS (K/V/P) reads done; reuse smem
  float* Od = (float*)smem;                   // [64][258] f32 (66048 B; 2-way banks)
  float* ML = (float*)(smem + 69632);         // [64][2] f32 (m, l)
  if (g == 1) {
#pragma unroll
    for (int fr = 0; fr < 2; ++fr) {
      const int r0 = wv*32 + fr*16 + l4*4;
#pragma unroll
      for (int r = 0; r < 4; ++r)
        if (l15 == 0) { ML[(r0 + r)*2] = m_run[fr][r]; ML[(r0 + r)*2 + 1] = l_run[fr][r]; }
#pragma unroll
      for (int nt2 = 0; nt2 < 16; ++nt2) {
        int dim = nt2*16 + l15;
#pragma unroll
        for (int r = 0; r < 4; ++r)
          Od[(r0 + r)*258 + dim] = oacc[fr][nt2][r];
      }
    }
  }
  __syncthreads();
  if (g == 0) {
#pragma unroll
    for (int fr = 0; fr < 2; ++fr) {
      const int r0 = wv*32 + fr*16 + l4*4;
      float fA[4], fB[4], inv_l[4];
#pragma unroll
      for (int r = 0; r < 4; ++r) {
        float mB = ML[(r0 + r)*2];
        float lB = ML[(r0 + r)*2 + 1];
        float m = fmaxf(m_run[fr][r], mB);
        fA[r] = exp2f(m_run[fr][r] - m);      // ==1 for dominant side
        fB[r] = exp2f(mB - m);                // ==0 when B fully masked (m=-1e30)
        inv_l[r] = 1.f / (l_run[fr][r]*fA[r] + lB*fB[r]);
      }
      const int srow0 = q0 + r0;
#pragma unroll
      for (int nt2 = 0; nt2 < 16; ++nt2) {
        int dim = nt2*16 + l15;
#pragma unroll
        for (int r = 0; r < 4; ++r) {
          int srow = srow0 + r;
          float ov = oacc[fr][nt2][r]*fA[r] + Od[(r0 + r)*258 + dim]*fB[r];
          float gv = C1[(size_t)srow*NALL + h*512 + 256 + dim];  // gate pre-activation
          float sg = 1.f / (1.f + __expf(-gv));
          attnb[(size_t)srow*(NH*HD) + h*HD + dim] = f2b(ov * inv_l[r] * sg);
        }
      }
    }
  }
}

extern "C" void kernel_launch(void* const* d_in, const int* in_sizes, int n_in,
                              void* d_out, int out_size, void* d_ws, size_t ws_size,
                              hipStream_t stream) {
  const float* hidden = (const float*)d_in[0];
  const float* cosb   = (const float*)d_in[1];
  const float* sinb   = (const float*)d_in[2];
  const float* qw     = (const float*)d_in[3];
  const float* kw     = (const float*)d_in[4];
  const float* vw     = (const float*)d_in[5];
  const float* ow     = (const float*)d_in[6];
  const float* qnw    = (const float*)d_in[7];
  const float* knw    = (const float*)d_in[8];
  float* out    = (float*)d_out;
  float* kcache = out + (size_t)S_LEN*HID;
  float* vcache = kcache + (size_t)NKV*MAXSEQ*HD;

  char* ws = (char*)d_ws;
  size_t off = 0;
  auto alloc = [&](size_t bytes) -> char* {
    char* p = ws + off; off += (bytes + 255) & ~(size_t)255; return p;
  };
  unsigned short* hidb  = (unsigned short*)alloc((size_t)S_LEN*HID*2);     //  8 MB
  unsigned short* wallb = (unsigned short*)alloc((size_t)NALL*HID*2);      // 36 MB
  unsigned short* wob   = (unsigned short*)alloc((size_t)HID*NH*HD*2);     // 16 MB
  float*          C1    = (float*)alloc((size_t)S_LEN*NALL*4);             // 72 MB
  unsigned short* qb    = (unsigned short*)alloc((size_t)NH*S_LEN*HD*2);   // 16 MB
  unsigned short* kb    = (unsigned short*)alloc((size_t)NKV*S_LEN*HD*2);  //  2 MB
  unsigned short* vtb   = (unsigned short*)alloc((size_t)NKV*HD*S_LEN*2);  //  2 MB
  unsigned short* attnb = (unsigned short*)alloc((size_t)S_LEN*NH*HD*2);   // 16 MB

  // all fp32->bf16 converts + cache-pad zeroing in one dispatch
  fused_cvt<<<32768, 256, 0, stream>>>(hidden, qw, kw, vw, ow,
                                       hidb, wallb, wob, kcache, vcache);

  // fused QKV projection: C1 = hidden @ [Wq|Wk|Wv]^T  (2048 x 9216)
  gemm_bt<128,128,4,4><<<dim3(NALL/128, S_LEN/128), 256, 0, stream>>>(
      hidb, wallb, C1, S_LEN, NALL, HID);

  // RMSNorm + RoPE + caches + V^T + q pre-scale
  postproc<<<dim3(S_LEN/4, 20), 256, 0, stream>>>(
      C1, cosb, sinb, qnw, knw, qb, kb, vtb, kcache, vcache);

  // flash attention + sigmoid gate -> attnb (S x H*HD bf16)
  // 512 blocks x 256 thr (4 waves: 2 row-halves x 2 split-K groups), 72KB LDS
  attn_kernel<<<512, 256, 0, stream>>>(qb, kb, vtb, C1, attnb);

  // hidden_out = attnb @ Wo^T  (2048 x 2048, K=4096)
  // 128x64 tiles -> grid 512 (was 256 at 128x128: only 1 block/CU)
  gemm_bt<128,64,4,2><<<dim3(HID/64, S_LEN/128), 256, 0, stream>>>(
      attnb, wob, out, S_LEN, HID, NH*HD);
}

// Round 6
// 421.835 us; speedup vs baseline: 1.6036x; 1.6036x over previous
//
#include <hip/hip_runtime.h>

#define S_LEN 2048
#define HID 2048
#define NH 16
#define NKV 2
#define HD 256
#define MAXSEQ 4096
#define NALL 9216   // 8192 qg | 512 k | 512 v
#define RD 64

typedef __attribute__((ext_vector_type(8))) short short8_t;   // 8 bf16 (4 VGPRs)
typedef __attribute__((ext_vector_type(4))) float float4_t;   // MFMA C/D

// DPP cross-lane over a 16-lane row (VALU pipe, not LDS): xor1, xor2, half-mirror, mirror
#define DPPF(x, ctrl) __builtin_bit_cast(float, __builtin_amdgcn_update_dpp( \
    __builtin_bit_cast(int, x), __builtin_bit_cast(int, x), ctrl, 0xF, 0xF, false))

__device__ __forceinline__ unsigned short f2b(float f) {
  union { float f; unsigned u; } v; v.f = f;
  unsigned u = v.u;
  return (unsigned short)((u + 0x7FFFu + ((u >> 16) & 1u)) >> 16);  // RNE, finite data
}

__device__ __forceinline__ void gload_lds16(const void* g, void* l) {
  __builtin_amdgcn_global_load_lds(
      (const __attribute__((address_space(1))) void*)g,
      (__attribute__((address_space(3))) void*)l, 16, 0, 0);
}

// ---------------- fused fp32->bf16 converts + cache-pad zeroing (one dispatch) ----------------
__global__ void fused_cvt(const float* __restrict__ hidden, const float* __restrict__ qw,
                          const float* __restrict__ kw, const float* __restrict__ vw,
                          const float* __restrict__ ow,
                          unsigned short* __restrict__ hidb, unsigned short* __restrict__ wallb,
                          unsigned short* __restrict__ wob,
                          float* __restrict__ kcache, float* __restrict__ vcache) {
  const long i = (long)blockIdx.x * 256 + threadIdx.x;
  const long N0 = 1048576, N1 = N0 + 4194304, N2 = N1 + 262144, N3 = N2 + 262144,
             N4 = N3 + 2097152;
  if (i < N4) {
    const float* s; unsigned short* d; long j;
    if (i < N0)      { s = hidden; d = hidb;  j = i; }
    else if (i < N1) { s = qw; d = wallb;                        j = i - N0; }
    else if (i < N2) { s = kw; d = wallb + (size_t)8192*HID;     j = i - N1; }
    else if (i < N3) { s = vw; d = wallb + (size_t)8704*HID;     j = i - N2; }
    else             { s = ow; d = wob;                          j = i - N3; }
    float4 v = ((const float4*)s)[j];
    short4 o;
    o.x = (short)f2b(v.x); o.y = (short)f2b(v.y);
    o.z = (short)f2b(v.z); o.w = (short)f2b(v.w);
    ((short4*)d)[j] = o;
  } else {
    long j = i - N4;                 // 0 .. 524287
    int region = (int)(j >> 17);     // 131072 float4 per pad region
    long o = j & 131071;
    float* base = (region < 2 ? kcache : vcache)
                + (size_t)(region & 1) * MAXSEQ * HD + (size_t)S_LEN * HD;
    float4 z; z.x = 0.f; z.y = 0.f; z.z = 0.f; z.w = 0.f;
    ((float4*)base)[o] = z;
  }
}

// ---------------- bf16 GEMM, C = A * B^T  (A: MxK, B: NxK row-major, C: MxN f32) ----------------
// m97 structure + BK=64 + XOR-swizzled LDS (chunk' = chunk ^ (row&7)).
template<int BM, int BN, int MI, int NI>
__global__ __launch_bounds__(256, 2) void gemm_bt(
    const unsigned short* __restrict__ A, const unsigned short* __restrict__ B,
    float* __restrict__ C, int M, int N, int K) {
  constexpr int BK = 64;
  __shared__ unsigned short As[BM * BK];
  __shared__ unsigned short Bs[BN * BK];
  const int tid = threadIdx.x;
  const int lane = tid & 63;
  const int w = tid >> 6;
  const int wr = w >> 1, wc = w & 1;
  const int l15 = lane & 15, l4 = lane >> 4;
  const int M0 = blockIdx.y * BM, N0 = blockIdx.x * BN;
  float4_t acc[MI][NI] = {};
  for (int kt = 0; kt < K; kt += BK) {
    __syncthreads();
#pragma unroll
    for (int i = 0; i < BM/32; ++i) {
      int c = tid + i*256;
      int row = c >> 3;
      gload_lds16(A + (size_t)(M0 + row)*K + kt + ((c & 7) ^ (row & 7))*8, (char*)As + c*16);
    }
#pragma unroll
    for (int i = 0; i < BN/32; ++i) {
      int c = tid + i*256;
      int row = c >> 3;
      gload_lds16(B + (size_t)(N0 + row)*K + kt + ((c & 7) ^ (row & 7))*8, (char*)Bs + c*16);
    }
    __syncthreads();
#pragma unroll
    for (int ks = 0; ks < 2; ++ks) {
      short8_t af[MI], bf[NI];
#pragma unroll
      for (int mi = 0; mi < MI; ++mi) {
        int row = wr*(BM/2) + mi*16 + l15;
        af[mi] = *(const short8_t*)&As[row*BK + ((ks*4 + l4) ^ (l15 & 7))*8];
      }
#pragma unroll
      for (int ni = 0; ni < NI; ++ni) {
        int row = wc*(BN/2) + ni*16 + l15;
        bf[ni] = *(const short8_t*)&Bs[row*BK + ((ks*4 + l4) ^ (l15 & 7))*8];
      }
#pragma unroll
      for (int mi = 0; mi < MI; ++mi)
#pragma unroll
        for (int ni = 0; ni < NI; ++ni)
          acc[mi][ni] = __builtin_amdgcn_mfma_f32_16x16x32_bf16(af[mi], bf[ni], acc[mi][ni], 0, 0, 0);
    }
  }
#pragma unroll
  for (int mi = 0; mi < MI; ++mi) {
    int rb = M0 + wr*(BM/2) + mi*16 + l4*4;
#pragma unroll
    for (int ni = 0; ni < NI; ++ni) {
      int col = N0 + wc*(BN/2) + ni*16 + l15;
#pragma unroll
      for (int r = 0; r < 4; ++r)
        C[(size_t)(rb + r)*N + col] = acc[mi][ni][r];
    }
  }
}

// ---------------- post: RMSNorm + RoPE + split + caches + V^T ----------------
__global__ void postproc(const float* __restrict__ C1,
                         const float* __restrict__ cosb, const float* __restrict__ sinb,
                         const float* __restrict__ qnw, const float* __restrict__ knw,
                         unsigned short* __restrict__ qb, unsigned short* __restrict__ kb,
                         unsigned short* __restrict__ vtb,
                         float* __restrict__ kcache, float* __restrict__ vcache) {
  const int w = threadIdx.x >> 6, lane = threadIdx.x & 63;
  const int s = blockIdx.x*4 + w;
  const int t = blockIdx.y;
  const int d = lane*4;
  const float* rowp;
  if (t < 16)      rowp = C1 + (size_t)s*NALL + t*512;
  else if (t < 18) rowp = C1 + (size_t)s*NALL + 8192 + (t-16)*256;
  else             rowp = C1 + (size_t)s*NALL + 8704 + (t-18)*256;
  float4 x = *(const float4*)(rowp + d);
  if (t >= 18) {
    int kvi = t - 18;
    *(float4*)(vcache + (size_t)kvi*MAXSEQ*HD + (size_t)s*HD + d) = x;
    unsigned short* vt = vtb + (size_t)kvi*HD*S_LEN;
    vt[(size_t)(d+0)*S_LEN + s] = f2b(x.x);
    vt[(size_t)(d+1)*S_LEN + s] = f2b(x.y);
    vt[(size_t)(d+2)*S_LEN + s] = f2b(x.z);
    vt[(size_t)(d+3)*S_LEN + s] = f2b(x.w);
    return;
  }
  float ss = x.x*x.x + x.y*x.y + x.z*x.z + x.w*x.w;
#pragma unroll
  for (int o = 32; o >= 1; o >>= 1) ss += __shfl_xor(ss, o, 64);
  float rn = rsqrtf(ss*(1.0f/256.0f) + 1e-6f);
  const float* nw = (t < 16) ? qnw : knw;
  float4 g = *(const float4*)(nw + d);
  float4 y;
  y.x = x.x*rn*(1.f+g.x); y.y = x.y*rn*(1.f+g.y);
  y.z = x.z*rn*(1.f+g.z); y.w = x.w*rn*(1.f+g.w);
  float px = __shfl_xor(y.x, 8, 64);
  float py = __shfl_xor(y.y, 8, 64);
  float pz = __shfl_xor(y.z, 8, 64);
  float pw = __shfl_xor(y.w, 8, 64);
  if (lane < 16) {
    float sgn = (lane & 8) ? 1.f : -1.f;
    float4 cs = *(const float4*)(cosb + (size_t)s*RD + d);
    float4 sn = *(const float4*)(sinb + (size_t)s*RD + d);
    y.x = y.x*cs.x + sgn*px*sn.x;
    y.y = y.y*cs.y + sgn*py*sn.y;
    y.z = y.z*cs.z + sgn*pz*sn.z;
    y.w = y.w*cs.w + sgn*pw*sn.w;
  }
  if (t < 16) {
    const float qs = 0.0625f * 1.44269504088896f;
    short4 o;
    o.x = (short)f2b(y.x*qs); o.y = (short)f2b(y.y*qs);
    o.z = (short)f2b(y.z*qs); o.w = (short)f2b(y.w*qs);
    *(short4*)(qb + (size_t)t*S_LEN*HD + (size_t)s*HD + d) = o;
  } else {
    int kvi = t - 16;
    *(float4*)(kcache + (size_t)kvi*MAXSEQ*HD + (size_t)s*HD + d) = y;
    short4 o;
    o.x = (short)f2b(y.x); o.y = (short)f2b(y.y);
    o.z = (short)f2b(y.z); o.w = (short)f2b(y.w);
    *(short4*)(kb + (size_t)kvi*S_LEN*HD + (size_t)s*HD + d) = o;
  }
}

// ---------------- flash attention + fused sigmoid gate ----------------
// R10: EQUAL-WORK blocks. 256 blocks (16 h x 16 pair-idx), 512 thr / 8 waves.
// Block (h, pi) processes q-tile pi then q-tile 31-pi sequentially:
// (pi+1) + (32-pi) = 33 k-tiles of 64 for EVERY block -> 1 block/CU, 8 waves
// = 2 waves/SIMD for the whole kernel. Zero tail, zero imbalance, no
// dispatcher pairing gamble (R8's occupancy decayed 16->8 waves per CU).
// Split-K by column-halves: waves 0-3 (g=0) take k-cols [0,32) of each
// 64-wide tile, waves 4-7 (g=1) take [32,64). R8's merge (HW-verified)
// runs once per phase. Numerics: m_run init = -1e29 (NOT -1e30) so a
// fully-masked group (pi=0, g=1, rows 0-15) gets p = exp2(-1e30-(-1e29))=0,
// zero l, zero O; merge weight exp2(-1e29 - mA) = 0 annihilates it.
// Sync skeleton per iter (HW-verified in R8):
//   B1 __syncthreads; stage K(4/thr)+V(4/thr); vmcnt(4) [K landed, V in
//   flight]; s_barrier; QK+softmax+P; __syncthreads (=V drain); PV.
// Register profile = R8 (~92 VGPR + 64 AGPR, cap 256 at (512,2)).
// LDS 72KB: Ks 64x256 (32KB) | VTs 256x64 (32KB) | 8x Pw 16x32 (8KB).
__global__ __launch_bounds__(512, 2) void attn_kernel(
    const unsigned short* __restrict__ qb, const unsigned short* __restrict__ kb,
    const unsigned short* __restrict__ vtb, const float* __restrict__ C1,
    unsigned short* __restrict__ attnb) {
  __shared__ char smem[73728];
  const int tid = threadIdx.x, lane = tid & 63, w = tid >> 6;  // w: 0..7
  const int g  = w >> 2;          // k-col group: cols [32g, 32g+32) of each tile
  const int wq = w & 3;           // row wave -> 16-q-row slice
  const int l15 = lane & 15, l4 = lane >> 4;
  unsigned short* Ks  = (unsigned short*)smem;             // 64 x 256
  unsigned short* VTs = (unsigned short*)(smem + 32768);   // 256 x 64
  unsigned short* Pw  = (unsigned short*)(smem + 65536 + w*1024);   // private 16x32
  const int b = blockIdx.x;       // 0..255
  const int h = b & 15;
  const int pi = b >> 4;          // 0..15
  const int kv = h >> 3;          // GROUPS = 8
  const unsigned short* Qb = qb + (size_t)h*S_LEN*HD;
  const unsigned short* Kb = kb + (size_t)kv*S_LEN*HD;
  const unsigned short* Vb = vtb + (size_t)kv*HD*S_LEN;
  for (int ph = 0; ph < 2; ++ph) {
    const int qt = ph ? (31 - pi) : pi;
    const int q0 = qt * 64;
    const int qrow = q0 + wq*16 + l15;
    short8_t qf[8];                           // Q fragment, A-layout
#pragma unroll
    for (int kk = 0; kk < 8; ++kk)
      qf[kk] = *(const short8_t*)(Qb + (size_t)qrow*HD + kk*32 + l4*8);
    float4_t oacc[16] = {};
    float m_run[4] = {-1e29f, -1e29f, -1e29f, -1e29f};  // -1e29: see header
    float l_run[4] = {0.f, 0.f, 0.f, 0.f};
    const int nT = qt + 1;                    // 64-wide k-tiles this phase
    for (int t = 0; t < nT; ++t) {
      const int k0 = t * 64;
      __syncthreads();                        // B1: prev iter's LDS reads done
#pragma unroll
      for (int i = 0; i < 4; ++i) {           // K tile: 64 rows x 256, swizzled src col
        int c = tid + i*512;
        int row = c >> 5;
        gload_lds16(Kb + (size_t)(k0 + row)*HD + ((c & 31) ^ (row & 7))*8, (char*)Ks + c*16);
      }
#pragma unroll
      for (int i = 0; i < 4; ++i) {           // V^T tile: 256 rows x 64
        int c = tid + i*512;
        int row = c >> 3;
        gload_lds16(Vb + (size_t)row*S_LEN + k0 + ((c & 7) ^ (row & 7))*8,
                    (char*)VTs + c*16);
      }
      asm volatile("s_waitcnt vmcnt(4)" ::: "memory");  // own K landed; V in flight
      __builtin_amdgcn_s_barrier();           // B2: all waves' K in LDS
      __builtin_amdgcn_sched_barrier(0);
      float4_t sacc[2] = {};
#pragma unroll
      for (int nt = 0; nt < 2; ++nt)
#pragma unroll
        for (int kk = 0; kk < 8; ++kk) {
          int krow = g*32 + nt*16 + l15;
          short8_t bfr = *(const short8_t*)&Ks[krow*HD + ((kk*4 + l4) ^ (l15 & 7))*8];
          sacc[nt] = __builtin_amdgcn_mfma_f32_16x16x32_bf16(qf[kk], bfr, sacc[nt], 0, 0, 0);
        }
      if (t == qt) {                          // causal mask on the diagonal tile
#pragma unroll
        for (int nt = 0; nt < 2; ++nt)
#pragma unroll
          for (int r = 0; r < 4; ++r)
            if (k0 + g*32 + nt*16 + l15 > q0 + wq*16 + l4*4 + r) sacc[nt][r] = -1e30f;
      }
      float m0[4], p[2][4];
#pragma unroll
      for (int r = 0; r < 4; ++r) {
        float v = fmaxf(sacc[0][r], sacc[1][r]);
        v = fmaxf(v, DPPF(v, 0xB1));          // quad_perm xor1
        v = fmaxf(v, DPPF(v, 0x4E));          // quad_perm xor2
        v = fmaxf(v, DPPF(v, 0x141));         // row_half_mirror
        v = fmaxf(v, DPPF(v, 0x140));         // row_mirror -> 16-lane max
        m0[r] = v;
      }
      int need = (m0[0] > m_run[0] + 4.f) | (m0[1] > m_run[1] + 4.f) |
                 (m0[2] > m_run[2] + 4.f) | (m0[3] > m_run[3] + 4.f);
      if (__any(need)) {                      // wave-uniform: rescale path
        float al[4];
#pragma unroll
        for (int r = 0; r < 4; ++r) {
          float mnew = fmaxf(m_run[r], m0[r]);
          al[r] = exp2f(m_run[r] - mnew);
          m_run[r] = mnew;
          l_run[r] *= al[r];
        }
#pragma unroll
        for (int nt2 = 0; nt2 < 16; ++nt2) {
          oacc[nt2][0] *= al[0];
          oacc[nt2][1] *= al[1];
          oacc[nt2][2] *= al[2];
          oacc[nt2][3] *= al[3];
        }
      }
#pragma unroll
      for (int r = 0; r < 4; ++r) {
        p[0][r] = exp2f(sacc[0][r] - m_run[r]);  // bounded by 2^4 (defer-max)
        p[1][r] = exp2f(sacc[1][r] - m_run[r]);
        float sum = p[0][r] + p[1][r];
        sum += DPPF(sum, 0xB1);
        sum += DPPF(sum, 0x4E);
        sum += DPPF(sum, 0x141);
        sum += DPPF(sum, 0x140);              // 16-lane sum
        l_run[r] += sum;
      }
      // P: D-layout -> A-layout via private LDS (same-wave RAW, lgkmcnt suffices)
#pragma unroll
      for (int nt = 0; nt < 2; ++nt)
#pragma unroll
        for (int r = 0; r < 4; ++r) {
          int prow = l4*4 + r;
          int pcol = nt*16 + l15;
          Pw[prow*32 + (((pcol >> 3) ^ ((prow >> 1) & 3)))*8 + (pcol & 7)] = f2b(p[nt][r]);
        }
      short8_t pf = *(const short8_t*)&Pw[l15*32 + ((l4 ^ ((l15 >> 1) & 3)))*8];
      __syncthreads();                        // B3: drains vmcnt(0) = V landed, all waves
#pragma unroll
      for (int nt2 = 0; nt2 < 16; ++nt2) {
        int vrow = nt2*16 + l15;
        short8_t v0 = *(const short8_t*)&VTs[vrow*64 + ((4*g + l4) ^ (vrow & 7))*8];
        oacc[nt2] = __builtin_amdgcn_mfma_f32_16x16x32_bf16(pf, v0, oacc[nt2], 0, 0, 0);
      }
    }
    // ------- split-K merge (per phase): g1 dumps to LDS, g0 combines + gate + store -------
    __syncthreads();                          // all LDS (K/V/P) reads done; reuse smem
    float* Od = (float*)smem;                 // [64][258] f32 (66048 B; 2-way banks)
    float* ML = (float*)(smem + 69632);       // [64][2] f32 (m, l)
    const int r0 = wq*16 + l4*4;              // local row base of this lane's 4 rows
    if (g == 1) {
#pragma unroll
      for (int r = 0; r < 4; ++r)
        if (l15 == 0) { ML[(r0 + r)*2] = m_run[r]; ML[(r0 + r)*2 + 1] = l_run[r]; }
#pragma unroll
      for (int nt2 = 0; nt2 < 16; ++nt2) {
        int dim = nt2*16 + l15;
#pragma unroll
        for (int r = 0; r < 4; ++r)
          Od[(r0 + r)*258 + dim] = oacc[nt2][r];
      }
    }
    __syncthreads();
    if (g == 0) {
      float fA[4], fB[4], inv_l[4];
#pragma unroll
      for (int r = 0; r < 4; ++r) {
        float mB = ML[(r0 + r)*2];
        float lB = ML[(r0 + r)*2 + 1];
        float m = fmaxf(m_run[r], mB);
        fA[r] = exp2f(m_run[r] - m);          // ==1 for dominant side
        fB[r] = exp2f(mB - m);                // ==0 when B fully masked (m=-1e29)
        inv_l[r] = 1.f / (l_run[r]*fA[r] + lB*fB[r]);
      }
      const int srow0 = q0 + r0;
#pragma unroll
      for (int nt2 = 0; nt2 < 16; ++nt2) {
        int dim = nt2*16 + l15;
#pragma unroll
        for (int r = 0; r < 4; ++r) {
          int srow = srow0 + r;
          float ov = oacc[nt2][r]*fA[r] + Od[(r0 + r)*258 + dim]*fB[r];
          float gv = C1[(size_t)srow*NALL + h*512 + 256 + dim];  // gate pre-activation
          float sg = 1.f / (1.f + __expf(-gv));
          attnb[(size_t)srow*(NH*HD) + h*HD + dim] = f2b(ov * inv_l[r] * sg);
        }
      }
    }
    // next phase's first B1 __syncthreads keeps Od reads ahead of re-staging
  }
}

extern "C" void kernel_launch(void* const* d_in, const int* in_sizes, int n_in,
                              void* d_out, int out_size, void* d_ws, size_t ws_size,
                              hipStream_t stream) {
  const float* hidden = (const float*)d_in[0];
  const float* cosb   = (const float*)d_in[1];
  const float* sinb   = (const float*)d_in[2];
  const float* qw     = (const float*)d_in[3];
  const float* kw     = (const float*)d_in[4];
  const float* vw     = (const float*)d_in[5];
  const float* ow     = (const float*)d_in[6];
  const float* qnw    = (const float*)d_in[7];
  const float* knw    = (const float*)d_in[8];
  float* out    = (float*)d_out;
  float* kcache = out + (size_t)S_LEN*HID;
  float* vcache = kcache + (size_t)NKV*MAXSEQ*HD;

  char* ws = (char*)d_ws;
  size_t off = 0;
  auto alloc = [&](size_t bytes) -> char* {
    char* p = ws + off; off += (bytes + 255) & ~(size_t)255; return p;
  };
  unsigned short* hidb  = (unsigned short*)alloc((size_t)S_LEN*HID*2);     //  8 MB
  unsigned short* wallb = (unsigned short*)alloc((size_t)NALL*HID*2);      // 36 MB
  unsigned short* wob   = (unsigned short*)alloc((size_t)HID*NH*HD*2);     // 16 MB
  float*          C1    = (float*)alloc((size_t)S_LEN*NALL*4);             // 72 MB
  unsigned short* qb    = (unsigned short*)alloc((size_t)NH*S_LEN*HD*2);   // 16 MB
  unsigned short* kb    = (unsigned short*)alloc((size_t)NKV*S_LEN*HD*2);  //  2 MB
  unsigned short* vtb   = (unsigned short*)alloc((size_t)NKV*HD*S_LEN*2);  //  2 MB
  unsigned short* attnb = (unsigned short*)alloc((size_t)S_LEN*NH*HD*2);   // 16 MB

  // all fp32->bf16 converts + cache-pad zeroing in one dispatch
  fused_cvt<<<32768, 256, 0, stream>>>(hidden, qw, kw, vw, ow,
                                       hidb, wallb, wob, kcache, vcache);

  // fused QKV projection: C1 = hidden @ [Wq|Wk|Wv]^T  (2048 x 9216)
  gemm_bt<128,128,4,4><<<dim3(NALL/128, S_LEN/128), 256, 0, stream>>>(
      hidb, wallb, C1, S_LEN, NALL, HID);

  // RMSNorm + RoPE + caches + V^T + q pre-scale
  postproc<<<dim3(S_LEN/4, 20), 256, 0, stream>>>(
      C1, cosb, sinb, qnw, knw, qb, kb, vtb, kcache, vcache);

  // flash attention + sigmoid gate -> attnb (S x H*HD bf16)
  // 256 equal-work blocks x 512 thr (8 waves), 72KB LDS, 1 block/CU flat
  attn_kernel<<<256, 512, 0, stream>>>(qb, kb, vtb, C1, attnb);

  // hidden_out = attnb @ Wo^T  (2048 x 2048, K=4096)
  // 128x64 tiles -> grid 512 (2 blocks/CU)
  gemm_bt<128,64,4,2><<<dim3(HID/64, S_LEN/128), 256, 0, stream>>>(
      attnb, wob, out, S_LEN, HID, NH*HD);
}

// Round 7
// 405.876 us; speedup vs baseline: 1.6666x; 1.0393x over previous
//
#include <hip/hip_runtime.h>

#define S_LEN 2048
#define HID 2048
#define NH 16
#define NKV 2
#define HD 256
#define MAXSEQ 4096
#define NALL 9216   // 8192 qg | 512 k | 512 v
#define RD 64

typedef __attribute__((ext_vector_type(8))) short short8_t;   // 8 bf16 (4 VGPRs)
typedef __attribute__((ext_vector_type(4))) float float4_t;   // MFMA C/D

// DPP cross-lane over a 16-lane row (VALU pipe, not LDS): xor1, xor2, half-mirror, mirror
#define DPPF(x, ctrl) __builtin_bit_cast(float, __builtin_amdgcn_update_dpp( \
    __builtin_bit_cast(int, x), __builtin_bit_cast(int, x), ctrl, 0xF, 0xF, false))

__device__ __forceinline__ unsigned short f2b(float f) {
  union { float f; unsigned u; } v; v.f = f;
  unsigned u = v.u;
  return (unsigned short)((u + 0x7FFFu + ((u >> 16) & 1u)) >> 16);  // RNE, finite data
}

__device__ __forceinline__ void gload_lds16(const void* g, void* l) {
  __builtin_amdgcn_global_load_lds(
      (const __attribute__((address_space(1))) void*)g,
      (__attribute__((address_space(3))) void*)l, 16, 0, 0);
}

// ---------------- fused fp32->bf16 converts + cache-pad zeroing (one dispatch) ----------------
__global__ void fused_cvt(const float* __restrict__ hidden, const float* __restrict__ qw,
                          const float* __restrict__ kw, const float* __restrict__ vw,
                          const float* __restrict__ ow,
                          unsigned short* __restrict__ hidb, unsigned short* __restrict__ wallb,
                          unsigned short* __restrict__ wob,
                          float* __restrict__ kcache, float* __restrict__ vcache) {
  const long i = (long)blockIdx.x * 256 + threadIdx.x;
  const long N0 = 1048576, N1 = N0 + 4194304, N2 = N1 + 262144, N3 = N2 + 262144,
             N4 = N3 + 2097152;
  if (i < N4) {
    const float* s; unsigned short* d; long j;
    if (i < N0)      { s = hidden; d = hidb;  j = i; }
    else if (i < N1) { s = qw; d = wallb;                        j = i - N0; }
    else if (i < N2) { s = kw; d = wallb + (size_t)8192*HID;     j = i - N1; }
    else if (i < N3) { s = vw; d = wallb + (size_t)8704*HID;     j = i - N2; }
    else             { s = ow; d = wob;                          j = i - N3; }
    float4 v = ((const float4*)s)[j];
    short4 o;
    o.x = (short)f2b(v.x); o.y = (short)f2b(v.y);
    o.z = (short)f2b(v.z); o.w = (short)f2b(v.w);
    ((short4*)d)[j] = o;
  } else {
    long j = i - N4;                 // 0 .. 524287
    int region = (int)(j >> 17);     // 131072 float4 per pad region
    long o = j & 131071;
    float* base = (region < 2 ? kcache : vcache)
                + (size_t)(region & 1) * MAXSEQ * HD + (size_t)S_LEN * HD;
    float4 z; z.x = 0.f; z.y = 0.f; z.z = 0.f; z.w = 0.f;
    ((float4*)base)[o] = z;
  }
}

// ---------------- bf16 GEMM, C = A * B^T  (A: MxK, B: NxK row-major, C: MxN f32) ----------------
// m97 structure + BK=64 + XOR-swizzled LDS (chunk' = chunk ^ (row&7)).
template<int BM, int BN, int MI, int NI>
__global__ __launch_bounds__(256, 2) void gemm_bt(
    const unsigned short* __restrict__ A, const unsigned short* __restrict__ B,
    float* __restrict__ C, int M, int N, int K) {
  constexpr int BK = 64;
  __shared__ unsigned short As[BM * BK];
  __shared__ unsigned short Bs[BN * BK];
  const int tid = threadIdx.x;
  const int lane = tid & 63;
  const int w = tid >> 6;
  const int wr = w >> 1, wc = w & 1;
  const int l15 = lane & 15, l4 = lane >> 4;
  const int M0 = blockIdx.y * BM, N0 = blockIdx.x * BN;
  float4_t acc[MI][NI] = {};
  for (int kt = 0; kt < K; kt += BK) {
    __syncthreads();
#pragma unroll
    for (int i = 0; i < BM/32; ++i) {
      int c = tid + i*256;
      int row = c >> 3;
      gload_lds16(A + (size_t)(M0 + row)*K + kt + ((c & 7) ^ (row & 7))*8, (char*)As + c*16);
    }
#pragma unroll
    for (int i = 0; i < BN/32; ++i) {
      int c = tid + i*256;
      int row = c >> 3;
      gload_lds16(B + (size_t)(N0 + row)*K + kt + ((c & 7) ^ (row & 7))*8, (char*)Bs + c*16);
    }
    __syncthreads();
#pragma unroll
    for (int ks = 0; ks < 2; ++ks) {
      short8_t af[MI], bf[NI];
#pragma unroll
      for (int mi = 0; mi < MI; ++mi) {
        int row = wr*(BM/2) + mi*16 + l15;
        af[mi] = *(const short8_t*)&As[row*BK + ((ks*4 + l4) ^ (l15 & 7))*8];
      }
#pragma unroll
      for (int ni = 0; ni < NI; ++ni) {
        int row = wc*(BN/2) + ni*16 + l15;
        bf[ni] = *(const short8_t*)&Bs[row*BK + ((ks*4 + l4) ^ (l15 & 7))*8];
      }
#pragma unroll
      for (int mi = 0; mi < MI; ++mi)
#pragma unroll
        for (int ni = 0; ni < NI; ++ni)
          acc[mi][ni] = __builtin_amdgcn_mfma_f32_16x16x32_bf16(af[mi], bf[ni], acc[mi][ni], 0, 0, 0);
    }
  }
#pragma unroll
  for (int mi = 0; mi < MI; ++mi) {
    int rb = M0 + wr*(BM/2) + mi*16 + l4*4;
#pragma unroll
    for (int ni = 0; ni < NI; ++ni) {
      int col = N0 + wc*(BN/2) + ni*16 + l15;
#pragma unroll
      for (int r = 0; r < 4; ++r)
        C[(size_t)(rb + r)*N + col] = acc[mi][ni][r];
    }
  }
}

// ---------------- post: RMSNorm + RoPE + split + caches + V^T ----------------
__global__ void postproc(const float* __restrict__ C1,
                         const float* __restrict__ cosb, const float* __restrict__ sinb,
                         const float* __restrict__ qnw, const float* __restrict__ knw,
                         unsigned short* __restrict__ qb, unsigned short* __restrict__ kb,
                         unsigned short* __restrict__ vtb,
                         float* __restrict__ kcache, float* __restrict__ vcache) {
  const int w = threadIdx.x >> 6, lane = threadIdx.x & 63;
  const int s = blockIdx.x*4 + w;
  const int t = blockIdx.y;
  const int d = lane*4;
  const float* rowp;
  if (t < 16)      rowp = C1 + (size_t)s*NALL + t*512;
  else if (t < 18) rowp = C1 + (size_t)s*NALL + 8192 + (t-16)*256;
  else             rowp = C1 + (size_t)s*NALL + 8704 + (t-18)*256;
  float4 x = *(const float4*)(rowp + d);
  if (t >= 18) {
    int kvi = t - 18;
    *(float4*)(vcache + (size_t)kvi*MAXSEQ*HD + (size_t)s*HD + d) = x;
    unsigned short* vt = vtb + (size_t)kvi*HD*S_LEN;
    vt[(size_t)(d+0)*S_LEN + s] = f2b(x.x);
    vt[(size_t)(d+1)*S_LEN + s] = f2b(x.y);
    vt[(size_t)(d+2)*S_LEN + s] = f2b(x.z);
    vt[(size_t)(d+3)*S_LEN + s] = f2b(x.w);
    return;
  }
  float ss = x.x*x.x + x.y*x.y + x.z*x.z + x.w*x.w;
#pragma unroll
  for (int o = 32; o >= 1; o >>= 1) ss += __shfl_xor(ss, o, 64);
  float rn = rsqrtf(ss*(1.0f/256.0f) + 1e-6f);
  const float* nw = (t < 16) ? qnw : knw;
  float4 g = *(const float4*)(nw + d);
  float4 y;
  y.x = x.x*rn*(1.f+g.x); y.y = x.y*rn*(1.f+g.y);
  y.z = x.z*rn*(1.f+g.z); y.w = x.w*rn*(1.f+g.w);
  float px = __shfl_xor(y.x, 8, 64);
  float py = __shfl_xor(y.y, 8, 64);
  float pz = __shfl_xor(y.z, 8, 64);
  float pw = __shfl_xor(y.w, 8, 64);
  if (lane < 16) {
    float sgn = (lane & 8) ? 1.f : -1.f;
    float4 cs = *(const float4*)(cosb + (size_t)s*RD + d);
    float4 sn = *(const float4*)(sinb + (size_t)s*RD + d);
    y.x = y.x*cs.x + sgn*px*sn.x;
    y.y = y.y*cs.y + sgn*py*sn.y;
    y.z = y.z*cs.z + sgn*pz*sn.z;
    y.w = y.w*cs.w + sgn*pw*sn.w;
  }
  if (t < 16) {
    const float qs = 0.0625f * 1.44269504088896f;
    short4 o;
    o.x = (short)f2b(y.x*qs); o.y = (short)f2b(y.y*qs);
    o.z = (short)f2b(y.z*qs); o.w = (short)f2b(y.w*qs);
    *(short4*)(qb + (size_t)t*S_LEN*HD + (size_t)s*HD + d) = o;
  } else {
    int kvi = t - 16;
    *(float4*)(kcache + (size_t)kvi*MAXSEQ*HD + (size_t)s*HD + d) = y;
    short4 o;
    o.x = (short)f2b(y.x); o.y = (short)f2b(y.y);
    o.z = (short)f2b(y.z); o.w = (short)f2b(y.w);
    *(short4*)(kb + (size_t)kvi*S_LEN*HD + (size_t)s*HD + d) = o;
  }
}

// ---------------- flash attention + fused sigmoid gate ----------------
// R11 = R10 equal-work skeleton + R6 double-buffered prefetch (both HW-verified):
//  * 256 blocks (16 h x 16 pi), 512 thr / 8 waves; block (h,pi) does q-tile pi
//    then q-tile 31-pi -> exactly 33 64-wide k-tiles per block, 1 block/CU flat.
//  * split-K by column-halves: waves 0-3 k-cols [0,32), waves 4-7 [32,64);
//    merge per phase (g1 dumps m/l/O to LDS, g0 combines+gate+stores).
//    m_run init -1e29 so a fully-masked group is annihilated by the merge.
//  * DOUBLE-BUFFERED staging with counted vmcnt (fixes R10's naked K latency:
//    issue-then-wait exposed ~300cyc L2 latency on every iter):
//      prologue: STAGE(tile0 -> buf0)
//      iter t:   STAGE(t+1 -> buf^1); s_waitcnt vmcnt(8) [tile-t landed,
//                next-tile in flight]; s_barrier; QK+softmax+P+PV from buf;
//                s_barrier
//    2 barriers/iter, no vmcnt(0) in steady state; pipeline refills only at
//    the 2 phase boundaries.
//  * LDS 136KB (<160KB, 1 blk/CU): Ks[2] 64x256 | VTs[2] 256x64 | 8x Pw 16x32.
//    Merge Od/ML overlay the buffer region; phase-entry __syncthreads protects.
//  * defer-max THR=4 kept (exact).
__global__ __launch_bounds__(512, 2) void attn_kernel(
    const unsigned short* __restrict__ qb, const unsigned short* __restrict__ kb,
    const unsigned short* __restrict__ vtb, const float* __restrict__ C1,
    unsigned short* __restrict__ attnb) {
  __shared__ char smem[139264];
  const int tid = threadIdx.x, lane = tid & 63, w = tid >> 6;  // w: 0..7
  const int g  = w >> 2;          // k-col group: cols [32g, 32g+32) of each tile
  const int wq = w & 3;           // row wave -> 16-q-row slice
  const int l15 = lane & 15, l4 = lane >> 4;
  unsigned short* Pw = (unsigned short*)(smem + 131072 + w*1024);  // private 16x32
  const int b = blockIdx.x;       // 0..255
  const int h = b & 15;
  const int pi = b >> 4;          // 0..15
  const int kv = h >> 3;          // GROUPS = 8
  const unsigned short* Qb = qb + (size_t)h*S_LEN*HD;
  const unsigned short* Kb = kb + (size_t)kv*S_LEN*HD;
  const unsigned short* Vb = vtb + (size_t)kv*HD*S_LEN;

  auto STAGE = [&](int k0s, int buf) {
    char* KsD = smem + buf*32768;            // 64 x 256 bf16
    char* VTD = smem + 65536 + buf*32768;    // 256 x 64 bf16
#pragma unroll
    for (int i = 0; i < 4; ++i) {            // K tile, swizzled source col
      int c = tid + i*512;
      int row = c >> 5;
      gload_lds16(Kb + (size_t)(k0s + row)*HD + ((c & 31) ^ (row & 7))*8, KsD + c*16);
    }
#pragma unroll
    for (int i = 0; i < 4; ++i) {            // V^T tile
      int c = tid + i*512;
      int row = c >> 3;
      gload_lds16(Vb + (size_t)row*S_LEN + k0s + ((c & 7) ^ (row & 7))*8, VTD + c*16);
    }
  };

  for (int ph = 0; ph < 2; ++ph) {
    const int qt = ph ? (31 - pi) : pi;
    const int q0 = qt * 64;
    const int qrow = q0 + wq*16 + l15;
    short8_t qf[8];                           // Q fragment, A-layout
#pragma unroll
    for (int kk = 0; kk < 8; ++kk)
      qf[kk] = *(const short8_t*)(Qb + (size_t)qrow*HD + kk*32 + l4*8);
    float4_t oacc[16] = {};
    float m_run[4] = {-1e29f, -1e29f, -1e29f, -1e29f};  // -1e29: see header
    float l_run[4] = {0.f, 0.f, 0.f, 0.f};
    const int nT = qt + 1;                    // 64-wide k-tiles this phase
    __syncthreads();                          // prev phase's merge reads done
    STAGE(0, 0);                              // prologue fill
    for (int t = 0; t < nT; ++t) {
      const int cur = t & 1;
      const int k0 = t * 64;
      if (t + 1 < nT) {
        STAGE((t + 1) * 64, cur ^ 1);         // next tile into other buffer
        asm volatile("s_waitcnt vmcnt(8)" ::: "memory");  // tile-t landed
      } else {
        asm volatile("s_waitcnt vmcnt(0)" ::: "memory");
      }
      __builtin_amdgcn_s_barrier();           // all waves' tile-t data in LDS
      __builtin_amdgcn_sched_barrier(0);
      const unsigned short* Ks  = (const unsigned short*)(smem + cur*32768);
      const unsigned short* VTs = (const unsigned short*)(smem + 65536 + cur*32768);
      float4_t sacc[2] = {};
#pragma unroll
      for (int nt = 0; nt < 2; ++nt)
#pragma unroll
        for (int kk = 0; kk < 8; ++kk) {
          int krow = g*32 + nt*16 + l15;
          short8_t bfr = *(const short8_t*)&Ks[krow*HD + ((kk*4 + l4) ^ (l15 & 7))*8];
          sacc[nt] = __builtin_amdgcn_mfma_f32_16x16x32_bf16(qf[kk], bfr, sacc[nt], 0, 0, 0);
        }
      if (t == qt) {                          // causal mask on the diagonal tile
#pragma unroll
        for (int nt = 0; nt < 2; ++nt)
#pragma unroll
          for (int r = 0; r < 4; ++r)
            if (k0 + g*32 + nt*16 + l15 > q0 + wq*16 + l4*4 + r) sacc[nt][r] = -1e30f;
      }
      float m0[4], p[2][4];
#pragma unroll
      for (int r = 0; r < 4; ++r) {
        float v = fmaxf(sacc[0][r], sacc[1][r]);
        v = fmaxf(v, DPPF(v, 0xB1));          // quad_perm xor1
        v = fmaxf(v, DPPF(v, 0x4E));          // quad_perm xor2
        v = fmaxf(v, DPPF(v, 0x141));         // row_half_mirror
        v = fmaxf(v, DPPF(v, 0x140));         // row_mirror -> 16-lane max
        m0[r] = v;
      }
      int need = (m0[0] > m_run[0] + 4.f) | (m0[1] > m_run[1] + 4.f) |
                 (m0[2] > m_run[2] + 4.f) | (m0[3] > m_run[3] + 4.f);
      if (__any(need)) {                      // wave-uniform: rescale path
        float al[4];
#pragma unroll
        for (int r = 0; r < 4; ++r) {
          float mnew = fmaxf(m_run[r], m0[r]);
          al[r] = exp2f(m_run[r] - mnew);
          m_run[r] = mnew;
          l_run[r] *= al[r];
        }
#pragma unroll
        for (int nt2 = 0; nt2 < 16; ++nt2) {
          oacc[nt2][0] *= al[0];
          oacc[nt2][1] *= al[1];
          oacc[nt2][2] *= al[2];
          oacc[nt2][3] *= al[3];
        }
      }
#pragma unroll
      for (int r = 0; r < 4; ++r) {
        p[0][r] = exp2f(sacc[0][r] - m_run[r]);  // bounded by 2^4 (defer-max)
        p[1][r] = exp2f(sacc[1][r] - m_run[r]);
        float sum = p[0][r] + p[1][r];
        sum += DPPF(sum, 0xB1);
        sum += DPPF(sum, 0x4E);
        sum += DPPF(sum, 0x141);
        sum += DPPF(sum, 0x140);              // 16-lane sum
        l_run[r] += sum;
      }
      // P: D-layout -> A-layout via private LDS (same-wave RAW, lgkmcnt suffices)
#pragma unroll
      for (int nt = 0; nt < 2; ++nt)
#pragma unroll
        for (int r = 0; r < 4; ++r) {
          int prow = l4*4 + r;
          int pcol = nt*16 + l15;
          Pw[prow*32 + (((pcol >> 3) ^ ((prow >> 1) & 3)))*8 + (pcol & 7)] = f2b(p[nt][r]);
        }
      short8_t pf = *(const short8_t*)&Pw[l15*32 + ((l4 ^ ((l15 >> 1) & 3)))*8];
#pragma unroll
      for (int nt2 = 0; nt2 < 16; ++nt2) {
        int vrow = nt2*16 + l15;
        short8_t v0 = *(const short8_t*)&VTs[vrow*64 + ((4*g + l4) ^ (vrow & 7))*8];
        oacc[nt2] = __builtin_amdgcn_mfma_f32_16x16x32_bf16(pf, v0, oacc[nt2], 0, 0, 0);
      }
      asm volatile("" ::: "memory");
      __builtin_amdgcn_s_barrier();           // reads of buf[cur] done (next STAGE reuses it)
    }
    // ------- split-K merge (per phase): g1 dumps to LDS, g0 combines + gate + store -------
    __syncthreads();                          // all LDS reads done; reuse smem for Od/ML
    float* Od = (float*)smem;                 // [64][258] f32 (66048 B; 2-way banks)
    float* ML = (float*)(smem + 69632);       // [64][2] f32 (m, l)
    const int r0 = wq*16 + l4*4;              // local row base of this lane's 4 rows
    if (g == 1) {
#pragma unroll
      for (int r = 0; r < 4; ++r)
        if (l15 == 0) { ML[(r0 + r)*2] = m_run[r]; ML[(r0 + r)*2 + 1] = l_run[r]; }
#pragma unroll
      for (int nt2 = 0; nt2 < 16; ++nt2) {
        int dim = nt2*16 + l15;
#pragma unroll
        for (int r = 0; r < 4; ++r)
          Od[(r0 + r)*258 + dim] = oacc[nt2][r];
      }
    }
    __syncthreads();
    if (g == 0) {
      float fA[4], fB[4], inv_l[4];
#pragma unroll
      for (int r = 0; r < 4; ++r) {
        float mB = ML[(r0 + r)*2];
        float lB = ML[(r0 + r)*2 + 1];
        float m = fmaxf(m_run[r], mB);
        fA[r] = exp2f(m_run[r] - m);          // ==1 for dominant side
        fB[r] = exp2f(mB - m);                // ==0 when B fully masked (m=-1e29)
        inv_l[r] = 1.f / (l_run[r]*fA[r] + lB*fB[r]);
      }
      const int srow0 = q0 + r0;
#pragma unroll
      for (int nt2 = 0; nt2 < 16; ++nt2) {
        int dim = nt2*16 + l15;
#pragma unroll
        for (int r = 0; r < 4; ++r) {
          int srow = srow0 + r;
          float ov = oacc[nt2][r]*fA[r] + Od[(r0 + r)*258 + dim]*fB[r];
          float gv = C1[(size_t)srow*NALL + h*512 + 256 + dim];  // gate pre-activation
          float sg = 1.f / (1.f + __expf(-gv));
          attnb[(size_t)srow*(NH*HD) + h*HD + dim] = f2b(ov * inv_l[r] * sg);
        }
      }
    }
    // next phase's entry __syncthreads keeps Od/ML reads ahead of re-staging
  }
}

extern "C" void kernel_launch(void* const* d_in, const int* in_sizes, int n_in,
                              void* d_out, int out_size, void* d_ws, size_t ws_size,
                              hipStream_t stream) {
  const float* hidden = (const float*)d_in[0];
  const float* cosb   = (const float*)d_in[1];
  const float* sinb   = (const float*)d_in[2];
  const float* qw     = (const float*)d_in[3];
  const float* kw     = (const float*)d_in[4];
  const float* vw     = (const float*)d_in[5];
  const float* ow     = (const float*)d_in[6];
  const float* qnw    = (const float*)d_in[7];
  const float* knw    = (const float*)d_in[8];
  float* out    = (float*)d_out;
  float* kcache = out + (size_t)S_LEN*HID;
  float* vcache = kcache + (size_t)NKV*MAXSEQ*HD;

  char* ws = (char*)d_ws;
  size_t off = 0;
  auto alloc = [&](size_t bytes) -> char* {
    char* p = ws + off; off += (bytes + 255) & ~(size_t)255; return p;
  };
  unsigned short* hidb  = (unsigned short*)alloc((size_t)S_LEN*HID*2);     //  8 MB
  unsigned short* wallb = (unsigned short*)alloc((size_t)NALL*HID*2);      // 36 MB
  unsigned short* wob   = (unsigned short*)alloc((size_t)HID*NH*HD*2);     // 16 MB
  float*          C1    = (float*)alloc((size_t)S_LEN*NALL*4);             // 72 MB
  unsigned short* qb    = (unsigned short*)alloc((size_t)NH*S_LEN*HD*2);   // 16 MB
  unsigned short* kb    = (unsigned short*)alloc((size_t)NKV*S_LEN*HD*2);  //  2 MB
  unsigned short* vtb   = (unsigned short*)alloc((size_t)NKV*HD*S_LEN*2);  //  2 MB
  unsigned short* attnb = (unsigned short*)alloc((size_t)S_LEN*NH*HD*2);   // 16 MB

  // all fp32->bf16 converts + cache-pad zeroing in one dispatch
  fused_cvt<<<32768, 256, 0, stream>>>(hidden, qw, kw, vw, ow,
                                       hidb, wallb, wob, kcache, vcache);

  // fused QKV projection: C1 = hidden @ [Wq|Wk|Wv]^T  (2048 x 9216)
  gemm_bt<128,128,4,4><<<dim3(NALL/128, S_LEN/128), 256, 0, stream>>>(
      hidb, wallb, C1, S_LEN, NALL, HID);

  // RMSNorm + RoPE + caches + V^T + q pre-scale
  postproc<<<dim3(S_LEN/4, 20), 256, 0, stream>>>(
      C1, cosb, sinb, qnw, knw, qb, kb, vtb, kcache, vcache);

  // flash attention + sigmoid gate -> attnb (S x H*HD bf16)
  // 256 equal-work blocks x 512 thr (8 waves), 136KB LDS dbuf, 1 block/CU flat
  attn_kernel<<<256, 512, 0, stream>>>(qb, kb, vtb, C1, attnb);

  // hidden_out = attnb @ Wo^T  (2048 x 2048, K=4096)
  // 128x64 tiles -> grid 512 (2 blocks/CU)
  gemm_bt<128,64,4,2><<<dim3(HID/64, S_LEN/128), 256, 0, stream>>>(
      attnb, wob, out, S_LEN, HID, NH*HD);
}